// Round 10
// baseline (102.715 us; speedup 1.0000x reference)
//
#include <hip/hip_runtime.h>

typedef float v2f __attribute__((ext_vector_type(2)));
typedef float v4f __attribute__((ext_vector_type(4)));

#define IMG 512
#define A_STR 40      // A[36][40]: r: gy=y0-10+r, c: gx=x0-12+c
#define T_STR 30      // BT[36][30] (cb=c-2), ET[26][30] overlays A, FT[16][30] overlays BT
#define WSLOT 2520    // floats per wave slice: A 1440 + BT 1080
#define NBLK 2048     // 8192 tiles (16x16) / 4 waves

__device__ __forceinline__ v2f lo2(v4f v) { return __builtin_shufflevector(v, v, 0, 1); }
__device__ __forceinline__ v2f hi2(v4f v) { return __builtin_shufflevector(v, v, 2, 3); }

__global__ __launch_bounds__(256, 4) void marl_fused(
    const float* __restrict__ prob,
    const float* __restrict__ cmap,
    const float* __restrict__ hmap,
    float* __restrict__ out)
{
    __shared__ __align__(16) float L[4 * WSLOT];   // 40320 B
    __shared__ float red[4];

    const float W[11] = {0.00881223f, 0.02714358f, 0.06511405f, 0.12164908f,
                         0.17699840f, 0.20056540f, 0.17699840f, 0.12164908f,
                         0.06511405f, 0.02714358f, 0.00881223f};
    v2f wv[11];
#pragma unroll
    for (int i = 0; i < 11; ++i) wv[i] = (v2f){W[i], W[i]};
    float w2 = 0.f;
#pragma unroll
    for (int i = 0; i < 11; ++i) w2 += W[i] * W[i];
    const float sumk2 = w2 * w2;
    const v2f z = {0.f, 0.f};

    const int tid  = threadIdx.x;
    const int lane = tid & 63, wave = tid >> 6;
    float* Aw = &L[wave * WSLOT];
    float* Bw = Aw + 1440;

    // tile: 16x16 outputs; 1024 tiles/image (32x32)
    const int T   = blockIdx.x * 4 + wave;
    const int b   = T >> 10, r10 = T & 1023;
    const int x0  = (r10 & 31) << 4, y0 = (r10 >> 5) << 4;
    const size_t base = (size_t)b << 18;

    // ---- stage A: h halo 36 rows x 40 cols (gx0 = x0-12, 16B aligned) ----
#pragma unroll
    for (int it = 0; it < 6; ++it) {
        int idx = lane + 64 * it;
        if (idx < 360) {
            int r = idx / 10, q = idx - 10 * r;
            int gy = y0 - 10 + r, gx0 = x0 - 12 + 4 * q;
            v4f v = {0.f, 0.f, 0.f, 0.f};
            if ((unsigned)gy < IMG) {
                const float* hr = &hmap[base + ((size_t)gy << 9)];
                if (gx0 >= 0 && gx0 + 3 < IMG) {
                    v = *(const v4f*)&hr[gx0];
                } else {
                    if ((unsigned)(gx0 + 0) < IMG) v.x = hr[gx0 + 0];
                    if ((unsigned)(gx0 + 1) < IMG) v.y = hr[gx0 + 1];
                    if ((unsigned)(gx0 + 2) < IMG) v.z = hr[gx0 + 2];
                    if ((unsigned)(gx0 + 3) < IMG) v.w = hr[gx0 + 3];
                }
            }
            *(v4f*)&Aw[r * A_STR + 4 * q] = v;
        }
    }

    // ---- preload c (P2 workers) and epilogue h/prob to registers ----
    const int p2p = lane % 13, p2o = lane / 13;   // P2/P3 worker coords (lane<52)
    float creg[8][2];
    if (lane < 52) {
#pragma unroll
        for (int cc = 0; cc < 8; ++cc) {
#pragma unroll
            for (int h = 0; h < 2; ++h) {
                int gy = y0 - 5 + 2 * p2p + h;
                int gx = x0 - 5 + 8 * p2o + cc;
                creg[cc][h] = ((unsigned)gy < IMG && (unsigned)gx < IMG)
                    ? cmap[base + ((size_t)gy << 9) + gx] : 0.f;
            }
        }
    }
    const int ox = lane & 15, oh = lane >> 4, oy0 = 4 * oh;
    float hreg[4], preg[4];
#pragma unroll
    for (int k = 0; k < 4; ++k) {
        size_t gi = base + ((size_t)(y0 + oy0 + k) << 9) + (x0 + ox);
        hreg[k] = hmap[gi];
        preg[k] = prob[gi];
    }

    // ================= barrier-free per-wave pipeline =================

    // ---- P1: convY(A[36][40]) -> BT[cb][by], cb = c-2 (0..35), by 0..25 ----
    if (lane < 60) {
        int q = lane % 10, run = lane / 10;    // run 0..5, by0 = 5*run
        int by0 = 5 * run;
        v2f aL[5] = {z, z, z, z, z}, aH[5] = {z, z, z, z, z};
#pragma unroll
        for (int i = 0; i < 15; ++i) {
            int rr = by0 + i; rr = rr > 35 ? 35 : rr;   // clamp (clipped outs discard)
            v4f a = *(const v4f*)&Aw[rr * A_STR + 4 * q];
            v2f lo = lo2(a), hi = hi2(a);
#pragma unroll
            for (int r = 0; r < 5; ++r) {
                int j = i - r;
                if (j >= 0 && j < 11) { aL[r] += wv[j] * lo; aH[r] += wv[j] * hi; }
            }
        }
#pragma unroll
        for (int r = 0; r < 5; ++r) {
            int by = by0 + r;
            if (by < 26) {
                int cb0 = 4 * q - 2;
                if ((unsigned)(cb0 + 0) < 36) Bw[(cb0 + 0) * T_STR + by] = aL[r].x;
                if ((unsigned)(cb0 + 1) < 36) Bw[(cb0 + 1) * T_STR + by] = aL[r].y;
                if ((unsigned)(cb0 + 2) < 36) Bw[(cb0 + 2) * T_STR + by] = aH[r].x;
                if ((unsigned)(cb0 + 3) < 36) Bw[(cb0 + 3) * T_STR + by] = aH[r].y;
            }
        }
    }

    // ---- P2: convX(BT) - c -> ET[ex][ey] (overlays Aw); zero outside image ----
    // worker: ey0 = 2*p2p (pairs), ex = 8*p2o + cc; taps cb = ex + j
    if (lane < 52) {
        v2f acc[8] = {z, z, z, z, z, z, z, z};
#pragma unroll
        for (int i = 0; i < 18; ++i) {
            int cb = 8 * p2o + i; cb = cb > 35 ? 35 : cb;
            v2f bb = *(const v2f*)&Bw[cb * T_STR + 2 * p2p];
#pragma unroll
            for (int cc = 0; cc < 8; ++cc) {
                int j = i - cc;
                if (j >= 0 && j < 11) acc[cc] += wv[j] * bb;
            }
        }
#pragma unroll
        for (int cc = 0; cc < 8; ++cc) {
            int ex = 8 * p2o + cc;
            if (ex < 26) {
                int gx = x0 - 5 + ex;
                bool xin = (unsigned)gx < IMG;
                v2f ev;
#pragma unroll
                for (int h = 0; h < 2; ++h) {
                    int gy = y0 - 5 + 2 * p2p + h;
                    ev[h] = (xin && (unsigned)gy < IMG) ? acc[cc][h] - creg[cc][h] : 0.f;
                }
                *(v2f*)&Aw[ex * T_STR + 2 * p2p] = ev;
            }
        }
    }

    // ---- P3: convX(ET) -> FT[ox][ey] (overlays Bw); taps ex = ox + j ----
    if (lane < 52) {
        int ox0 = 4 * p2o;                      // ox0 in {0,4,8,12}
        v2f acc[4] = {z, z, z, z};
#pragma unroll
        for (int i = 0; i < 14; ++i) {
            v2f ee = *(const v2f*)&Aw[(ox0 + i) * T_STR + 2 * p2p];
#pragma unroll
            for (int cc = 0; cc < 4; ++cc) {
                int j = i - cc;
                if (j >= 0 && j < 11) acc[cc] += wv[j] * ee;
            }
        }
#pragma unroll
        for (int cc = 0; cc < 4; ++cc)
            *(v2f*)&Bw[(ox0 + cc) * T_STR + 2 * p2p] = acc[cc];
    }

    // ---- P4: convY(FT) -> corr + fused epilogue (all 64 lanes) ----
    float partial = 0.f;
    {
        float win[14];
#pragma unroll
        for (int k = 0; k < 7; ++k)
            *(v2f*)&win[2 * k] = *(const v2f*)&Bw[ox * T_STR + oy0 + 2 * k];
#pragma unroll
        for (int k = 0; k < 4; ++k) {
            float corr = 0.f;
#pragma unroll
            for (int j = 0; j < 11; ++j) corr += W[j] * win[k + j];
            float h_ = hreg[k], p_ = preg[k];
            float logp = __logf(h_ > 0.5f ? p_ + 1e-8f : 1.f - p_ + 1e-8f);
            float delta = 1.f - 2.f * h_;
            partial += (2.f * delta * corr + sumk2) * logp;
        }
    }

    // ---- reduction: wave shuffle -> one barrier -> one atomic per block ----
#pragma unroll
    for (int off = 32; off > 0; off >>= 1)
        partial += __shfl_down(partial, off, 64);
    if (lane == 0) red[wave] = partial;
    __syncthreads();
    if (tid == 0) {
        float s = red[0] + red[1] + red[2] + red[3];
        atomicAdd(out, s * -0.125f);   // loss = -sum / B
    }
}

extern "C" void kernel_launch(void* const* d_in, const int* in_sizes, int n_in,
                              void* d_out, int out_size, void* d_ws, size_t ws_size,
                              hipStream_t stream) {
    const float* prob = (const float*)d_in[0];
    const float* cmap = (const float*)d_in[1];
    const float* hmap = (const float*)d_in[2];
    float* out = (float*)d_out;

    hipMemsetAsync(out, 0, sizeof(float), stream);

    marl_fused<<<dim3(NBLK), dim3(256), 0, stream>>>(prob, cmap, hmap, out);
}